// Round 3
// baseline (248.740 us; speedup 1.0000x reference)
//
#include <hip/hip_runtime.h>
#include <hip/hip_bf16.h>

// BertSelfAttention on MI355X (gfx950). B=2, S=2048, H=1024, heads=16, dh=64.
// Inputs/output float32. Internal compute bf16 MFMA.
//
// Round 8: attn occupancy push — single-buffered K/V.
//   Round-7 counters: MfmaUtil 26 / VALUBusy 49 / Occupancy 31% / HBM 7%:
//   latency-bound at 2 blocks/CU (LDS 72KB was the limiter, VGPR only 60).
//   - Ks/Vs single-buffered (m97 2-barrier structure): LDS 72->40KB ->
//     4 blocks/CU = 32 waves/CU. Intra-block prefetch overlap traded for
//     TLP across 4 resident blocks (m114: wave-level overlap captures it).
//   - one shared arena so the f32 cross-half combine scratch can span the
//     K+V region legally.
//   - __launch_bounds__(512, 8) pins VGPR <= 64 (currently 60).
//   Math/layouts identical to round 7 (verified): in-register P via
//   pack2bf + v_permlane32_swap_b32, block-internal kv-split, fixed-max
//   softmax in log2 domain, denominator via VALU sum + shfl_xor(32).

typedef __bf16 bf16x8 __attribute__((ext_vector_type(8)));
typedef __bf16 bf16x4 __attribute__((ext_vector_type(4)));
typedef float f32x4 __attribute__((ext_vector_type(4)));
typedef float f32x16 __attribute__((ext_vector_type(16)));
typedef int i32x4 __attribute__((ext_vector_type(4)));

static constexpr int H = 1024;
static constexpr int S = 2048;
static constexpr int NH = 16;
static constexpr int DH = 64;
static constexpr float L2E = 1.4426950408889634f;

#if __has_builtin(__builtin_amdgcn_exp2f)
#define EXP2F(x) __builtin_amdgcn_exp2f(x)
#else
#define EXP2F(x) __builtin_exp2f(x)
#endif

__device__ inline void gll16(const void* g, void* l) {
  __builtin_amdgcn_global_load_lds(
      (const __attribute__((address_space(1))) void*)g,
      (__attribute__((address_space(3))) void*)l, 16, 0, 0);
}

// pack two f32 -> one dword of 2 bf16 (lo in bits 0-15)
__device__ inline int pack2bf(float lo, float hi) {
  unsigned short a = __builtin_bit_cast(unsigned short, (__bf16)lo);
  unsigned short b = __builtin_bit_cast(unsigned short, (__bf16)hi);
  return (int)(((unsigned)b << 16) | (unsigned)a);
}

// v_permlane32_swap_b32: swaps the hi 32 lanes of a with the lo 32 lanes of b.
__device__ inline void plswap(int& a, int& b) {
  asm volatile("v_permlane32_swap_b32 %0, %1" : "+v"(a), "+v"(b));
}

// Fused converts: blocks [0,2048) convert X f32->bf16; blocks [2048,2816)
// transpose-convert Wq/Wk/Wv -> Wt bf16 [n][k] via padded-LDS 64x64 tiles.
__global__ __launch_bounds__(256) void convert_kernel(
    const float* __restrict__ X, const float* __restrict__ W0,
    const float* __restrict__ W1, const float* __restrict__ W2,
    __bf16* __restrict__ Xb, __bf16* __restrict__ Wt) {
  __shared__ float T[64][65];
  const int bid = blockIdx.x, tid = threadIdx.x;
  if (bid < 2048) {
    size_t i = ((size_t)bid * 256 + tid) * 8;
    float4 f0 = *(const float4*)(X + i);
    float4 f1 = *(const float4*)(X + i + 4);
    bf16x8 o;
    o[0] = (__bf16)f0.x; o[1] = (__bf16)f0.y; o[2] = (__bf16)f0.z; o[3] = (__bf16)f0.w;
    o[4] = (__bf16)f1.x; o[5] = (__bf16)f1.y; o[6] = (__bf16)f1.z; o[7] = (__bf16)f1.w;
    *(bf16x8*)(Xb + i) = o;
    return;
  }
  const int wid = bid - 2048;
  const int z = wid >> 8, t = wid & 255;
  const int k0 = (t >> 4) * 64, n0 = (t & 15) * 64;
  const float* W = z == 0 ? W0 : (z == 1 ? W1 : W2);
  __bf16* Wo = Wt + (size_t)z * H * H;
#pragma unroll
  for (int it = 0; it < 4; ++it) {
    int r = it * 16 + (tid >> 4), c = (tid & 15) * 4;
    *(float4*)&T[r][c] = *(const float4*)&W[(size_t)(k0 + r) * H + n0 + c];
  }
  __syncthreads();
#pragma unroll
  for (int it = 0; it < 4; ++it) {
    int n = it * 16 + (tid >> 4), c0 = (tid & 15) * 4;
    bf16x4 o;
#pragma unroll
    for (int j = 0; j < 4; ++j) o[j] = (__bf16)T[c0 + j][n];
    *(bf16x4*)&Wo[(size_t)(n0 + n) * H + k0 + c0] = o;
  }
}

// Fused QKV GEMM: grid (24, 32). blockIdx.x: [0..7]=Q, [8..15]=K, [16..23]=V.
// 128x128 tile, BK=64. Q out [bh][d][s] (scaled 0.125*L2E), K out [bh][s][d],
// V out [bh][d][s].
__global__ __launch_bounds__(256, 3) void qkv_gemm_kernel(
    const __bf16* __restrict__ Xb, const __bf16* __restrict__ Wt,
    const float* __restrict__ bq, const float* __restrict__ bk,
    const float* __restrict__ bv,
    __bf16* __restrict__ Qt, __bf16* __restrict__ K, __bf16* __restrict__ Vt)
{
  __shared__ __bf16 As[128 * 64];   // [m][k], 8 chunks/row, XOR-swizzled
  __shared__ __bf16 Bs[128 * 64];   // [n][k], same

  const int tid = threadIdx.x, lane = tid & 63, w = tid >> 6;
  const int quad = lane >> 4, l16 = lane & 15;
  const int wsel = blockIdx.x >> 3;
  const int n0 = (blockIdx.x & 7) * 128;
  const int m0 = blockIdx.y * 128;
  const int wr = w & 1, wc = w >> 1;

  const __bf16* Wsel = Wt + (size_t)wsel * H * H;
  const float* bias = wsel == 0 ? bq : (wsel == 1 ? bk : bv);

  const __bf16* aptr[4];
  const __bf16* bptr[4];
#pragma unroll
  for (int i = 0; i < 4; ++i) {
    int s = w * 256 + i * 64 + lane;
    int row = s >> 3, col = s & 7, sc = col ^ (row & 7);
    aptr[i] = Xb + (size_t)(m0 + row) * H + sc * 8;
    bptr[i] = Wsel + (size_t)(n0 + row) * H + sc * 8;
  }

  f32x4 acc[4][4] = {};

  for (int k0 = 0; k0 < H; k0 += 64) {
    __syncthreads();
#pragma unroll
    for (int i = 0; i < 4; ++i) {
      gll16(aptr[i] + k0, &As[(w * 256 + i * 64) * 8]);
      gll16(bptr[i] + k0, &Bs[(w * 256 + i * 64) * 8]);
    }
    __syncthreads();
#pragma unroll
    for (int kc = 0; kc < 2; ++kc) {
      bf16x8 af[4], bfr[4];
#pragma unroll
      for (int t = 0; t < 4; ++t) {
        int ra = wr * 64 + t * 16 + l16;
        af[t] = *(const bf16x8*)&As[ra * 64 + (((kc * 4 + quad) ^ (ra & 7)) * 8)];
        int rb = wc * 64 + t * 16 + l16;
        bfr[t] = *(const bf16x8*)&Bs[rb * 64 + (((kc * 4 + quad) ^ (rb & 7)) * 8)];
      }
#pragma unroll
      for (int t = 0; t < 4; ++t)
#pragma unroll
        for (int u = 0; u < 4; ++u)
          acc[t][u] = __builtin_amdgcn_mfma_f32_16x16x32_bf16(af[t], bfr[u], acc[t][u], 0, 0, 0);
    }
  }

  const float qscale = 0.125f * L2E;
#pragma unroll
  for (int u = 0; u < 4; ++u) {
    int n = n0 + wc * 64 + u * 16 + l16;
    int head = n >> 6, d = n & 63;
    float bias_v = bias[n];
#pragma unroll
    for (int t = 0; t < 4; ++t) {
      int srow = m0 + wr * 64 + t * 16 + quad * 4;
      int b = srow >> 11, si = srow & (S - 1);
      int bh = b * NH + head;
      if (wsel == 1) {
        __bf16* dst = K + ((size_t)bh * S + si) * DH + d;
#pragma unroll
        for (int r = 0; r < 4; ++r)
          dst[(size_t)r * DH] = (__bf16)(acc[t][u][r] + bias_v);
      } else {
        float scl = wsel == 0 ? qscale : 1.0f;
        __bf16* outp = wsel == 0 ? Qt : Vt;
        bf16x4 o;
#pragma unroll
        for (int r = 0; r < 4; ++r) o[r] = (__bf16)((acc[t][u][r] + bias_v) * scl);
        *(bf16x4*)&outp[((size_t)bh * DH + d) * S + si] = o;
      }
    }
  }
}

// Flash attention, transposed scores, fixed-max softmax, 32x32x16 MFMA,
// in-register P (permlane32_swap), block-internal kv-split, single-buffered.
// grid (16, 32) XCD-swizzled, 512 threads (8 waves). Wave w: q-cols
// [q0 + (w&3)*32, +32), kv half (w>>2). KV tile 64, 2 barriers/tile.
__global__ __launch_bounds__(512, 8) void attn_kernel(
    const __bf16* __restrict__ Qt, const __bf16* __restrict__ K,
    const __bf16* __restrict__ Vt, const float* __restrict__ mask,
    float* __restrict__ out)
{
  // 40KB arena: Ks [2 half][64kv][64d] (16KB) | Vs [2 half][64d][64kv] (16KB)
  //             | Ms f32[2048] (8KB). Epilogue reuses [0,32KB) as f32 Os and
  //             the Ms region as Ls.
  __shared__ __bf16 SM[20480];
  __bf16* Ksb = SM;              // + wh*4096
  __bf16* Vsb = SM + 8192;       // + wh*4096
  float*  Ms  = (float*)(SM + 16384);

  const int tid = threadIdx.x, lane = tid & 63, w = tid >> 6;  // w: 0..7
  const int l31 = lane & 31, hi = lane >> 5;
  const int wl = w & 3, wh = w >> 2;

  // XCD-aware bijective swizzle: 512 blocks -> 64 consecutive (4 bh) per XCD.
  const int lin = blockIdx.y * 16 + blockIdx.x;
  const int v = (lin & 7) * 64 + (lin >> 3);
  const int bh = v >> 4, b = bh >> 4, h = bh & 15;
  const int q0 = (v & 15) * 128;

  const __bf16* Qb = Qt + (size_t)bh * DH * S;   // [d][s], pre-scaled
  const __bf16* Kb = K + (size_t)bh * S * DH;    // [s][d]
  const __bf16* Vb = Vt + (size_t)bh * DH * S;   // [d][s]
  const float* mb = mask + (size_t)b * S;

  // stage mask once (512 threads x 4 floats), pre-scaled by log2(e)
  {
    int idx = tid * 4;
    float4 mv = *(const float4*)&mb[idx];
    float4 sv = {mv.x * L2E, mv.y * L2E, mv.z * L2E, mv.w * L2E};
    *(float4*)&Ms[idx] = sv;
  }

  // Q B-fragments (32x32x16): qf[kc][j] = Qt[d = kc*16 + hi*8 + j][q]
  const int q = q0 + wl * 32 + l31;
  bf16x8 qf[4];
#pragma unroll
  for (int kc = 0; kc < 4; ++kc)
#pragma unroll
    for (int j = 0; j < 8; ++j)
      qf[kc][j] = Qb[(size_t)(kc * 16 + hi * 8 + j) * S + q];

  // staging: waves 0-3 stage half 0, waves 4-7 stage half 1 (same wl pattern)
  const int kvbase = wh * 1024;
  const __bf16* kptr[2];
  const __bf16* vptr[2];
#pragma unroll
  for (int i = 0; i < 2; ++i) {
    int s = wl * 128 + i * 64 + lane;
    int row = s >> 3, col = s & 7, sc = col ^ (row & 7);
    kptr[i] = Kb + (size_t)(kvbase + row) * DH + sc * 8;   // + st*64*DH later
    vptr[i] = Vb + (size_t)row * S + kvbase + sc * 8;      // + st*64 later
  }

  f32x16 o0 = {}, o1 = {};   // O^T accumulators, dsub 0 / 1 (d = row, q = col)
  float dl = 0.0f;           // per-lane partial of denominator sum_kv P

  for (int st = 0; st < 16; ++st) {
    __syncthreads();   // all prior reads of Ks/Vs done -> safe to overwrite
#pragma unroll
    for (int i = 0; i < 2; ++i) {
      gll16(kptr[i] + (size_t)st * 64 * DH,
            &Ksb[wh * 4096 + (wl * 128 + i * 64 + lane) * 8]);
      gll16(vptr[i] + st * 64,
            &Vsb[wh * 4096 + (wl * 128 + i * 64 + lane) * 8]);
    }
    __syncthreads();   // implicit vmcnt(0): tile staged and visible
    const __bf16* Kc = &Ksb[wh * 4096];
    const __bf16* Vc = &Vsb[wh * 4096];
    const int kvabs = kvbase + st * 64;

#pragma unroll
    for (int kvsub = 0; kvsub < 2; ++kvsub) {
      const int rk = kvsub * 32 + l31;
      // C-init = mask*log2e: row kv = 8g + 4hi + r  ->  Ms[kvabs+kvsub*32+...]
      f32x16 cc;
#pragma unroll
      for (int g = 0; g < 4; ++g) {
        float4 m4 = *(const float4*)&Ms[kvabs + kvsub * 32 + g * 8 + hi * 4];
        cc[4 * g + 0] = m4.x; cc[4 * g + 1] = m4.y;
        cc[4 * g + 2] = m4.z; cc[4 * g + 3] = m4.w;
      }
      __builtin_amdgcn_s_setprio(1);
#pragma unroll
      for (int kc = 0; kc < 4; ++kc) {
        bf16x8 af = *(const bf16x8*)&Kc[rk * 64 + (((kc * 2 + hi) ^ (l31 & 7)) * 8)];
        cc = __builtin_amdgcn_mfma_f32_32x32x16_bf16(af, qf[kc], cc, 0, 0, 0);
      }
      __builtin_amdgcn_s_setprio(0);

      // P = exp2(S^T); pack to bf16 dwords; denominator partial (f32 sum)
      float p[16];
#pragma unroll
      for (int r = 0; r < 16; ++r) { p[r] = EXP2F(cc[r]); dl += p[r]; }
      int a0 = pack2bf(p[0],  p[1]),  b0 = pack2bf(p[2],  p[3]);
      int a1 = pack2bf(p[4],  p[5]),  b1 = pack2bf(p[6],  p[7]);
      int a2 = pack2bf(p[8],  p[9]),  b2 = pack2bf(p[10], p[11]);
      int a3 = pack2bf(p[12], p[13]), b3 = pack2bf(p[14], p[15]);
      // lane l / l+32 exchange: builds PV B-frag dword halves in-register
      plswap(a0, a1); plswap(b0, b1);   // -> frag pc = 2*kvsub
      plswap(a2, a3); plswap(b2, b3);   // -> frag pc = 2*kvsub + 1
      i32x4 pi0 = {a0, b0, a1, b1};
      i32x4 pi1 = {a2, b2, a3, b3};
      bf16x8 pf0 = __builtin_bit_cast(bf16x8, pi0);
      bf16x8 pf1 = __builtin_bit_cast(bf16x8, pi1);

      // O^T += V^T P^T for the two 16-kv chunks of this kvsub
      __builtin_amdgcn_s_setprio(1);
#pragma unroll
      for (int pp = 0; pp < 2; ++pp) {
        const int pc = kvsub * 2 + pp;
        const bf16x8 pf = pp ? pf1 : pf0;
        bf16x8 vf0 = *(const bf16x8*)&Vc[l31 * 64 + (((pc * 2 + hi) ^ (l31 & 7)) * 8)];
        o0 = __builtin_amdgcn_mfma_f32_32x32x16_bf16(vf0, pf, o0, 0, 0, 0);
        bf16x8 vf1 = *(const bf16x8*)&Vc[(32 + l31) * 64 + (((pc * 2 + hi) ^ (l31 & 7)) * 8)];
        o1 = __builtin_amdgcn_mfma_f32_32x32x16_bf16(vf1, pf, o1, 0, 0, 0);
      }
      __builtin_amdgcn_s_setprio(0);
    }
  }

  // per-wave denominator for this kv half (lanes l / l+32 are complementary)
  float lsum = dl + __shfl_xor(dl, 32);

  // cross-half combine: Os spans the Ks+Vs region (32KB), Ls reuses Ms.
  __syncthreads();
  float* Os = (float*)SM;
  float* Ls = Ms;
  if (wh == 1) {
#pragma unroll
    for (int g = 0; g < 4; ++g) {
      int s0 = (2 * g + hi) ^ (l31 & 7);
      float4 t0 = {o0[4 * g + 0], o0[4 * g + 1], o0[4 * g + 2], o0[4 * g + 3]};
      *(float4*)&Os[(wl * 32 + l31) * 64 + s0 * 4] = t0;
      int s1 = (8 + 2 * g + hi) ^ (l31 & 7);
      float4 t1 = {o1[4 * g + 0], o1[4 * g + 1], o1[4 * g + 2], o1[4 * g + 3]};
      *(float4*)&Os[(wl * 32 + l31) * 64 + s1 * 4] = t1;
    }
    if (hi == 0) Ls[wl * 32 + l31] = lsum;
  }
  __syncthreads();
  if (wh == 0) {
    float ltot = lsum + Ls[wl * 32 + l31];
    float invl = 1.0f / ltot;
#pragma unroll
    for (int g = 0; g < 4; ++g) {
      int d0 = g * 8 + hi * 4;
      int s0 = (2 * g + hi) ^ (l31 & 7);
      float4 u0 = *(const float4*)&Os[(wl * 32 + l31) * 64 + s0 * 4];
      float4 r0 = {(o0[4 * g + 0] + u0.x) * invl, (o0[4 * g + 1] + u0.y) * invl,
                   (o0[4 * g + 2] + u0.z) * invl, (o0[4 * g + 3] + u0.w) * invl};
      *(float4*)&out[((size_t)b * S + q) * H + h * DH + d0] = r0;
      int s1 = (8 + 2 * g + hi) ^ (l31 & 7);
      float4 u1 = *(const float4*)&Os[(wl * 32 + l31) * 64 + s1 * 4];
      float4 r1 = {(o1[4 * g + 0] + u1.x) * invl, (o1[4 * g + 1] + u1.y) * invl,
                   (o1[4 * g + 2] + u1.z) * invl, (o1[4 * g + 3] + u1.w) * invl};
      *(float4*)&out[((size_t)b * S + q) * H + h * DH + 32 + d0] = r1;
    }
  }
}

extern "C" void kernel_launch(void* const* d_in, const int* in_sizes, int n_in,
                              void* d_out, int out_size, void* d_ws, size_t ws_size,
                              hipStream_t stream) {
  const float* X    = (const float*)d_in[0];
  const float* mask = (const float*)d_in[1];
  const float* Wq   = (const float*)d_in[2];
  const float* bq   = (const float*)d_in[3];
  const float* Wk   = (const float*)d_in[4];
  const float* bk   = (const float*)d_in[5];
  const float* Wv   = (const float*)d_in[6];
  const float* bv   = (const float*)d_in[7];
  float* out = (float*)d_out;

  const size_t per = (size_t)2 * NH * S * DH;   // 4M elems
  __bf16* Qws  = (__bf16*)d_ws;                 // 8MB  [bh][d][s]
  __bf16* Kws  = Qws + per;                     // 8MB  [bh][s][d]
  __bf16* Vtws = Kws + per;                     // 8MB  [bh][d][s]

  // GEMM-phase scratch inside d_out (16MB); attn overwrites all of d_out.
  __bf16* Xb = (__bf16*)d_out;                  // 8MB
  __bf16* Wt = Xb + per;                        // 3 x 2MB

  convert_kernel<<<2816, 256, 0, stream>>>(X, Wq, Wk, Wv, Xb, Wt);
  qkv_gemm_kernel<<<dim3(24, 32), 256, 0, stream>>>(Xb, Wt, bq, bk, bv,
                                                    Qws, Kws, Vtws);
  attn_kernel<<<dim3(16, 32), 512, 0, stream>>>(Qws, Kws, Vtws, mask, out);
}

// Round 4
// 160.790 us; speedup vs baseline: 1.5470x; 1.5470x over previous
//
#include <hip/hip_runtime.h>
#include <hip/hip_bf16.h>

// BertSelfAttention on MI355X (gfx950). B=2, S=2048, H=1024, heads=16, dh=64.
// Inputs/output float32. Internal compute bf16 MFMA.
//
// Round 9: fix round-8 spill regression.
//   Round-8 counters: VGPR_Count 32 (was 60), FETCH 174MB / WRITE 200MB
//   (was 12.4/16) -> __launch_bounds__(512,8) over-capped VGPR; all live
//   state (o0/o1 = 32 regs, qf = 16) spilled to scratch. attn 52.9->143.7us.
//   - revert to __launch_bounds__(512, 4) (round-7-verified: 60 VGPR, 0 spill).
//   - keep round-8 single-buffered 40KB arena: LDS-limited occupancy is now
//     4 blocks/CU; at 60 VGPR the 8 wave-slots/SIMD are reachable.
//   Math/layouts identical to round 7 (verified): in-register P via
//   pack2bf + v_permlane32_swap_b32, block-internal kv-split, fixed-max
//   softmax in log2 domain, denominator via VALU sum + shfl_xor(32).

typedef __bf16 bf16x8 __attribute__((ext_vector_type(8)));
typedef __bf16 bf16x4 __attribute__((ext_vector_type(4)));
typedef float f32x4 __attribute__((ext_vector_type(4)));
typedef float f32x16 __attribute__((ext_vector_type(16)));
typedef int i32x4 __attribute__((ext_vector_type(4)));

static constexpr int H = 1024;
static constexpr int S = 2048;
static constexpr int NH = 16;
static constexpr int DH = 64;
static constexpr float L2E = 1.4426950408889634f;

#if __has_builtin(__builtin_amdgcn_exp2f)
#define EXP2F(x) __builtin_amdgcn_exp2f(x)
#else
#define EXP2F(x) __builtin_exp2f(x)
#endif

__device__ inline void gll16(const void* g, void* l) {
  __builtin_amdgcn_global_load_lds(
      (const __attribute__((address_space(1))) void*)g,
      (__attribute__((address_space(3))) void*)l, 16, 0, 0);
}

// pack two f32 -> one dword of 2 bf16 (lo in bits 0-15)
__device__ inline int pack2bf(float lo, float hi) {
  unsigned short a = __builtin_bit_cast(unsigned short, (__bf16)lo);
  unsigned short b = __builtin_bit_cast(unsigned short, (__bf16)hi);
  return (int)(((unsigned)b << 16) | (unsigned)a);
}

// v_permlane32_swap_b32: swaps the hi 32 lanes of a with the lo 32 lanes of b.
__device__ inline void plswap(int& a, int& b) {
  asm volatile("v_permlane32_swap_b32 %0, %1" : "+v"(a), "+v"(b));
}

// Fused converts: blocks [0,2048) convert X f32->bf16; blocks [2048,2816)
// transpose-convert Wq/Wk/Wv -> Wt bf16 [n][k] via padded-LDS 64x64 tiles.
__global__ __launch_bounds__(256) void convert_kernel(
    const float* __restrict__ X, const float* __restrict__ W0,
    const float* __restrict__ W1, const float* __restrict__ W2,
    __bf16* __restrict__ Xb, __bf16* __restrict__ Wt) {
  __shared__ float T[64][65];
  const int bid = blockIdx.x, tid = threadIdx.x;
  if (bid < 2048) {
    size_t i = ((size_t)bid * 256 + tid) * 8;
    float4 f0 = *(const float4*)(X + i);
    float4 f1 = *(const float4*)(X + i + 4);
    bf16x8 o;
    o[0] = (__bf16)f0.x; o[1] = (__bf16)f0.y; o[2] = (__bf16)f0.z; o[3] = (__bf16)f0.w;
    o[4] = (__bf16)f1.x; o[5] = (__bf16)f1.y; o[6] = (__bf16)f1.z; o[7] = (__bf16)f1.w;
    *(bf16x8*)(Xb + i) = o;
    return;
  }
  const int wid = bid - 2048;
  const int z = wid >> 8, t = wid & 255;
  const int k0 = (t >> 4) * 64, n0 = (t & 15) * 64;
  const float* W = z == 0 ? W0 : (z == 1 ? W1 : W2);
  __bf16* Wo = Wt + (size_t)z * H * H;
#pragma unroll
  for (int it = 0; it < 4; ++it) {
    int r = it * 16 + (tid >> 4), c = (tid & 15) * 4;
    *(float4*)&T[r][c] = *(const float4*)&W[(size_t)(k0 + r) * H + n0 + c];
  }
  __syncthreads();
#pragma unroll
  for (int it = 0; it < 4; ++it) {
    int n = it * 16 + (tid >> 4), c0 = (tid & 15) * 4;
    bf16x4 o;
#pragma unroll
    for (int j = 0; j < 4; ++j) o[j] = (__bf16)T[c0 + j][n];
    *(bf16x4*)&Wo[(size_t)(n0 + n) * H + k0 + c0] = o;
  }
}

// Fused QKV GEMM: grid (24, 32). blockIdx.x: [0..7]=Q, [8..15]=K, [16..23]=V.
// 128x128 tile, BK=64. Q out [bh][d][s] (scaled 0.125*L2E), K out [bh][s][d],
// V out [bh][d][s].
__global__ __launch_bounds__(256, 3) void qkv_gemm_kernel(
    const __bf16* __restrict__ Xb, const __bf16* __restrict__ Wt,
    const float* __restrict__ bq, const float* __restrict__ bk,
    const float* __restrict__ bv,
    __bf16* __restrict__ Qt, __bf16* __restrict__ K, __bf16* __restrict__ Vt)
{
  __shared__ __bf16 As[128 * 64];   // [m][k], 8 chunks/row, XOR-swizzled
  __shared__ __bf16 Bs[128 * 64];   // [n][k], same

  const int tid = threadIdx.x, lane = tid & 63, w = tid >> 6;
  const int quad = lane >> 4, l16 = lane & 15;
  const int wsel = blockIdx.x >> 3;
  const int n0 = (blockIdx.x & 7) * 128;
  const int m0 = blockIdx.y * 128;
  const int wr = w & 1, wc = w >> 1;

  const __bf16* Wsel = Wt + (size_t)wsel * H * H;
  const float* bias = wsel == 0 ? bq : (wsel == 1 ? bk : bv);

  const __bf16* aptr[4];
  const __bf16* bptr[4];
#pragma unroll
  for (int i = 0; i < 4; ++i) {
    int s = w * 256 + i * 64 + lane;
    int row = s >> 3, col = s & 7, sc = col ^ (row & 7);
    aptr[i] = Xb + (size_t)(m0 + row) * H + sc * 8;
    bptr[i] = Wsel + (size_t)(n0 + row) * H + sc * 8;
  }

  f32x4 acc[4][4] = {};

  for (int k0 = 0; k0 < H; k0 += 64) {
    __syncthreads();
#pragma unroll
    for (int i = 0; i < 4; ++i) {
      gll16(aptr[i] + k0, &As[(w * 256 + i * 64) * 8]);
      gll16(bptr[i] + k0, &Bs[(w * 256 + i * 64) * 8]);
    }
    __syncthreads();
#pragma unroll
    for (int kc = 0; kc < 2; ++kc) {
      bf16x8 af[4], bfr[4];
#pragma unroll
      for (int t = 0; t < 4; ++t) {
        int ra = wr * 64 + t * 16 + l16;
        af[t] = *(const bf16x8*)&As[ra * 64 + (((kc * 4 + quad) ^ (ra & 7)) * 8)];
        int rb = wc * 64 + t * 16 + l16;
        bfr[t] = *(const bf16x8*)&Bs[rb * 64 + (((kc * 4 + quad) ^ (rb & 7)) * 8)];
      }
#pragma unroll
      for (int t = 0; t < 4; ++t)
#pragma unroll
        for (int u = 0; u < 4; ++u)
          acc[t][u] = __builtin_amdgcn_mfma_f32_16x16x32_bf16(af[t], bfr[u], acc[t][u], 0, 0, 0);
    }
  }

  const float qscale = 0.125f * L2E;
#pragma unroll
  for (int u = 0; u < 4; ++u) {
    int n = n0 + wc * 64 + u * 16 + l16;
    int head = n >> 6, d = n & 63;
    float bias_v = bias[n];
#pragma unroll
    for (int t = 0; t < 4; ++t) {
      int srow = m0 + wr * 64 + t * 16 + quad * 4;
      int b = srow >> 11, si = srow & (S - 1);
      int bh = b * NH + head;
      if (wsel == 1) {
        __bf16* dst = K + ((size_t)bh * S + si) * DH + d;
#pragma unroll
        for (int r = 0; r < 4; ++r)
          dst[(size_t)r * DH] = (__bf16)(acc[t][u][r] + bias_v);
      } else {
        float scl = wsel == 0 ? qscale : 1.0f;
        __bf16* outp = wsel == 0 ? Qt : Vt;
        bf16x4 o;
#pragma unroll
        for (int r = 0; r < 4; ++r) o[r] = (__bf16)((acc[t][u][r] + bias_v) * scl);
        *(bf16x4*)&outp[((size_t)bh * DH + d) * S + si] = o;
      }
    }
  }
}

// Flash attention, transposed scores, fixed-max softmax, 32x32x16 MFMA,
// in-register P (permlane32_swap), block-internal kv-split, single-buffered.
// grid (16, 32) XCD-swizzled, 512 threads (8 waves). Wave w: q-cols
// [q0 + (w&3)*32, +32), kv half (w>>2). KV tile 64, 2 barriers/tile.
__global__ __launch_bounds__(512, 4) void attn_kernel(
    const __bf16* __restrict__ Qt, const __bf16* __restrict__ K,
    const __bf16* __restrict__ Vt, const float* __restrict__ mask,
    float* __restrict__ out)
{
  // 40KB arena: Ks [2 half][64kv][64d] (16KB) | Vs [2 half][64d][64kv] (16KB)
  //             | Ms f32[2048] (8KB). Epilogue reuses [0,32KB) as f32 Os and
  //             the Ms region as Ls.
  __shared__ __bf16 SM[20480];
  __bf16* Ksb = SM;              // + wh*4096
  __bf16* Vsb = SM + 8192;       // + wh*4096
  float*  Ms  = (float*)(SM + 16384);

  const int tid = threadIdx.x, lane = tid & 63, w = tid >> 6;  // w: 0..7
  const int l31 = lane & 31, hi = lane >> 5;
  const int wl = w & 3, wh = w >> 2;

  // XCD-aware bijective swizzle: 512 blocks -> 64 consecutive (4 bh) per XCD.
  const int lin = blockIdx.y * 16 + blockIdx.x;
  const int v = (lin & 7) * 64 + (lin >> 3);
  const int bh = v >> 4, b = bh >> 4, h = bh & 15;
  const int q0 = (v & 15) * 128;

  const __bf16* Qb = Qt + (size_t)bh * DH * S;   // [d][s], pre-scaled
  const __bf16* Kb = K + (size_t)bh * S * DH;    // [s][d]
  const __bf16* Vb = Vt + (size_t)bh * DH * S;   // [d][s]
  const float* mb = mask + (size_t)b * S;

  // stage mask once (512 threads x 4 floats), pre-scaled by log2(e)
  {
    int idx = tid * 4;
    float4 mv = *(const float4*)&mb[idx];
    float4 sv = {mv.x * L2E, mv.y * L2E, mv.z * L2E, mv.w * L2E};
    *(float4*)&Ms[idx] = sv;
  }

  // Q B-fragments (32x32x16): qf[kc][j] = Qt[d = kc*16 + hi*8 + j][q]
  const int q = q0 + wl * 32 + l31;
  bf16x8 qf[4];
#pragma unroll
  for (int kc = 0; kc < 4; ++kc)
#pragma unroll
    for (int j = 0; j < 8; ++j)
      qf[kc][j] = Qb[(size_t)(kc * 16 + hi * 8 + j) * S + q];

  // staging: waves 0-3 stage half 0, waves 4-7 stage half 1 (same wl pattern)
  const int kvbase = wh * 1024;
  const __bf16* kptr[2];
  const __bf16* vptr[2];
#pragma unroll
  for (int i = 0; i < 2; ++i) {
    int s = wl * 128 + i * 64 + lane;
    int row = s >> 3, col = s & 7, sc = col ^ (row & 7);
    kptr[i] = Kb + (size_t)(kvbase + row) * DH + sc * 8;   // + st*64*DH later
    vptr[i] = Vb + (size_t)row * S + kvbase + sc * 8;      // + st*64 later
  }

  f32x16 o0 = {}, o1 = {};   // O^T accumulators, dsub 0 / 1 (d = row, q = col)
  float dl = 0.0f;           // per-lane partial of denominator sum_kv P

  for (int st = 0; st < 16; ++st) {
    __syncthreads();   // all prior reads of Ks/Vs done -> safe to overwrite
#pragma unroll
    for (int i = 0; i < 2; ++i) {
      gll16(kptr[i] + (size_t)st * 64 * DH,
            &Ksb[wh * 4096 + (wl * 128 + i * 64 + lane) * 8]);
      gll16(vptr[i] + st * 64,
            &Vsb[wh * 4096 + (wl * 128 + i * 64 + lane) * 8]);
    }
    __syncthreads();   // implicit vmcnt(0): tile staged and visible
    const __bf16* Kc = &Ksb[wh * 4096];
    const __bf16* Vc = &Vsb[wh * 4096];
    const int kvabs = kvbase + st * 64;

#pragma unroll
    for (int kvsub = 0; kvsub < 2; ++kvsub) {
      const int rk = kvsub * 32 + l31;
      // C-init = mask*log2e: row kv = 8g + 4hi + r  ->  Ms[kvabs+kvsub*32+...]
      f32x16 cc;
#pragma unroll
      for (int g = 0; g < 4; ++g) {
        float4 m4 = *(const float4*)&Ms[kvabs + kvsub * 32 + g * 8 + hi * 4];
        cc[4 * g + 0] = m4.x; cc[4 * g + 1] = m4.y;
        cc[4 * g + 2] = m4.z; cc[4 * g + 3] = m4.w;
      }
      __builtin_amdgcn_s_setprio(1);
#pragma unroll
      for (int kc = 0; kc < 4; ++kc) {
        bf16x8 af = *(const bf16x8*)&Kc[rk * 64 + (((kc * 2 + hi) ^ (l31 & 7)) * 8)];
        cc = __builtin_amdgcn_mfma_f32_32x32x16_bf16(af, qf[kc], cc, 0, 0, 0);
      }
      __builtin_amdgcn_s_setprio(0);

      // P = exp2(S^T); pack to bf16 dwords; denominator partial (f32 sum)
      float p[16];
#pragma unroll
      for (int r = 0; r < 16; ++r) { p[r] = EXP2F(cc[r]); dl += p[r]; }
      int a0 = pack2bf(p[0],  p[1]),  b0 = pack2bf(p[2],  p[3]);
      int a1 = pack2bf(p[4],  p[5]),  b1 = pack2bf(p[6],  p[7]);
      int a2 = pack2bf(p[8],  p[9]),  b2 = pack2bf(p[10], p[11]);
      int a3 = pack2bf(p[12], p[13]), b3 = pack2bf(p[14], p[15]);
      // lane l / l+32 exchange: builds PV B-frag dword halves in-register
      plswap(a0, a1); plswap(b0, b1);   // -> frag pc = 2*kvsub
      plswap(a2, a3); plswap(b2, b3);   // -> frag pc = 2*kvsub + 1
      i32x4 pi0 = {a0, b0, a1, b1};
      i32x4 pi1 = {a2, b2, a3, b3};
      bf16x8 pf0 = __builtin_bit_cast(bf16x8, pi0);
      bf16x8 pf1 = __builtin_bit_cast(bf16x8, pi1);

      // O^T += V^T P^T for the two 16-kv chunks of this kvsub
      __builtin_amdgcn_s_setprio(1);
#pragma unroll
      for (int pp = 0; pp < 2; ++pp) {
        const int pc = kvsub * 2 + pp;
        const bf16x8 pf = pp ? pf1 : pf0;
        bf16x8 vf0 = *(const bf16x8*)&Vc[l31 * 64 + (((pc * 2 + hi) ^ (l31 & 7)) * 8)];
        o0 = __builtin_amdgcn_mfma_f32_32x32x16_bf16(vf0, pf, o0, 0, 0, 0);
        bf16x8 vf1 = *(const bf16x8*)&Vc[(32 + l31) * 64 + (((pc * 2 + hi) ^ (l31 & 7)) * 8)];
        o1 = __builtin_amdgcn_mfma_f32_32x32x16_bf16(vf1, pf, o1, 0, 0, 0);
      }
      __builtin_amdgcn_s_setprio(0);
    }
  }

  // per-wave denominator for this kv half (lanes l / l+32 are complementary)
  float lsum = dl + __shfl_xor(dl, 32);

  // cross-half combine: Os spans the Ks+Vs region (32KB), Ls reuses Ms.
  __syncthreads();
  float* Os = (float*)SM;
  float* Ls = Ms;
  if (wh == 1) {
#pragma unroll
    for (int g = 0; g < 4; ++g) {
      int s0 = (2 * g + hi) ^ (l31 & 7);
      float4 t0 = {o0[4 * g + 0], o0[4 * g + 1], o0[4 * g + 2], o0[4 * g + 3]};
      *(float4*)&Os[(wl * 32 + l31) * 64 + s0 * 4] = t0;
      int s1 = (8 + 2 * g + hi) ^ (l31 & 7);
      float4 t1 = {o1[4 * g + 0], o1[4 * g + 1], o1[4 * g + 2], o1[4 * g + 3]};
      *(float4*)&Os[(wl * 32 + l31) * 64 + s1 * 4] = t1;
    }
    if (hi == 0) Ls[wl * 32 + l31] = lsum;
  }
  __syncthreads();
  if (wh == 0) {
    float ltot = lsum + Ls[wl * 32 + l31];
    float invl = 1.0f / ltot;
#pragma unroll
    for (int g = 0; g < 4; ++g) {
      int d0 = g * 8 + hi * 4;
      int s0 = (2 * g + hi) ^ (l31 & 7);
      float4 u0 = *(const float4*)&Os[(wl * 32 + l31) * 64 + s0 * 4];
      float4 r0 = {(o0[4 * g + 0] + u0.x) * invl, (o0[4 * g + 1] + u0.y) * invl,
                   (o0[4 * g + 2] + u0.z) * invl, (o0[4 * g + 3] + u0.w) * invl};
      *(float4*)&out[((size_t)b * S + q) * H + h * DH + d0] = r0;
      int s1 = (8 + 2 * g + hi) ^ (l31 & 7);
      float4 u1 = *(const float4*)&Os[(wl * 32 + l31) * 64 + s1 * 4];
      float4 r1 = {(o1[4 * g + 0] + u1.x) * invl, (o1[4 * g + 1] + u1.y) * invl,
                   (o1[4 * g + 2] + u1.z) * invl, (o1[4 * g + 3] + u1.w) * invl};
      *(float4*)&out[((size_t)b * S + q) * H + h * DH + 32 + d0] = r1;
    }
  }
}

extern "C" void kernel_launch(void* const* d_in, const int* in_sizes, int n_in,
                              void* d_out, int out_size, void* d_ws, size_t ws_size,
                              hipStream_t stream) {
  const float* X    = (const float*)d_in[0];
  const float* mask = (const float*)d_in[1];
  const float* Wq   = (const float*)d_in[2];
  const float* bq   = (const float*)d_in[3];
  const float* Wk   = (const float*)d_in[4];
  const float* bk   = (const float*)d_in[5];
  const float* Wv   = (const float*)d_in[6];
  const float* bv   = (const float*)d_in[7];
  float* out = (float*)d_out;

  const size_t per = (size_t)2 * NH * S * DH;   // 4M elems
  __bf16* Qws  = (__bf16*)d_ws;                 // 8MB  [bh][d][s]
  __bf16* Kws  = Qws + per;                     // 8MB  [bh][s][d]
  __bf16* Vtws = Kws + per;                     // 8MB  [bh][d][s]

  // GEMM-phase scratch inside d_out (16MB); attn overwrites all of d_out.
  __bf16* Xb = (__bf16*)d_out;                  // 8MB
  __bf16* Wt = Xb + per;                        // 3 x 2MB

  convert_kernel<<<2816, 256, 0, stream>>>(X, Wq, Wk, Wv, Xb, Wt);
  qkv_gemm_kernel<<<dim3(24, 32), 256, 0, stream>>>(Xb, Wt, bq, bk, bv,
                                                    Qws, Kws, Vtws);
  attn_kernel<<<dim3(16, 32), 512, 0, stream>>>(Qws, Kws, Vtws, mask, out);
}